// Round 1
// baseline (1973.034 us; speedup 1.0000x reference)
//
#include <hip/hip_runtime.h>
#include <hip/hip_bf16.h>
#include <hip/hip_fp16.h>

#define VOCAB 5000
#define EMB 128
#define H1D 128
#define H2D 64
#define QD 64
#define TDIM 256
#define BDIM 512
#define LTEXT 30
#define LSTEPS 29

typedef __attribute__((ext_vector_type(4))) float f32x4;
typedef __attribute__((ext_vector_type(8))) _Float16 f16x8;

__device__ __forceinline__ float sigmoidf_(float x) {
    return 1.0f / (1.0f + __expf(-x));
}

// ---------------------------------------------------------------------------
// Kernel A: the sequential decoder. 128 blocks x 256 threads, 4 rows/block.
// Each batch row is an independent sequence -> no inter-block communication.
// ---------------------------------------------------------------------------
__global__ __launch_bounds__(256) void k_recurrent(
    const float* __restrict__ key, const float* __restrict__ values,
    const float* __restrict__ mask, const int* __restrict__ text,
    const float* __restrict__ emb,
    const float* __restrict__ Wih1, const float* __restrict__ Whh1,
    const float* __restrict__ bih1, const float* __restrict__ bhh1,
    const float* __restrict__ Wih2, const float* __restrict__ Whh2,
    const float* __restrict__ bih2, const float* __restrict__ bhh2,
    const float* __restrict__ Wq, const float* __restrict__ bq,
    _Float16* __restrict__ h2ctx)
{
    __shared__ float s_inp[4][192];     // [x(128) | ctx(64)]
    __shared__ float s_h1[4][H1D], s_c1[4][H1D];
    __shared__ float s_h2[4][H2D], s_c2[4][H2D];
    __shared__ float s_g1[4][4 * H1D];
    __shared__ float s_g2[4][4 * H2D];
    __shared__ float s_q[4][QD];
    __shared__ float s_ma[4][TDIM];
    __shared__ float s_ctx[4][QD];

    const int tid = threadIdx.x;
    const int blk = blockIdx.x;

    for (int i = tid; i < 4 * H1D; i += 256) { s_h1[i >> 7][i & 127] = 0.f; s_c1[i >> 7][i & 127] = 0.f; }
    for (int i = tid; i < 4 * H2D; i += 256) { s_h2[i >> 6][i & 63] = 0.f; s_c2[i >> 6][i & 63] = 0.f; s_ctx[i >> 6][i & 63] = 0.f; }
    __syncthreads();

    for (int t = 0; t < LSTEPS; ++t) {
        // (a) inp = [emb[text[b,t]], ctx]
        for (int i = tid; i < 4 * 192; i += 256) {
            int r = i / 192, k = i % 192;
            int b = blk * 4 + r;
            if (k < 128) {
                int tok = text[b * LTEXT + t];
                s_inp[r][k] = emb[(size_t)tok * EMB + k];
            } else {
                s_inp[r][k] = s_ctx[r][k - 128];
            }
        }
        __syncthreads();

        // (b) g1 = inp @ Wih1^T + h1 @ Whh1^T + biases  (thread: gates tid, tid+256; 4 rows)
        {
            float a0[4] = {0.f, 0.f, 0.f, 0.f}, a1[4] = {0.f, 0.f, 0.f, 0.f};
            const f32x4* w0 = (const f32x4*)(Wih1 + (size_t)tid * 192);
            const f32x4* w1 = (const f32x4*)(Wih1 + (size_t)(tid + 256) * 192);
            #pragma unroll 4
            for (int k4 = 0; k4 < 48; ++k4) {
                f32x4 wa = w0[k4], wb = w1[k4];
                #pragma unroll
                for (int r = 0; r < 4; ++r) {
                    f32x4 x = *(const f32x4*)&s_inp[r][k4 * 4];
                    a0[r] += wa.x * x.x + wa.y * x.y + wa.z * x.z + wa.w * x.w;
                    a1[r] += wb.x * x.x + wb.y * x.y + wb.z * x.z + wb.w * x.w;
                }
            }
            const f32x4* v0 = (const f32x4*)(Whh1 + (size_t)tid * 128);
            const f32x4* v1 = (const f32x4*)(Whh1 + (size_t)(tid + 256) * 128);
            #pragma unroll 4
            for (int k4 = 0; k4 < 32; ++k4) {
                f32x4 wa = v0[k4], wb = v1[k4];
                #pragma unroll
                for (int r = 0; r < 4; ++r) {
                    f32x4 h = *(const f32x4*)&s_h1[r][k4 * 4];
                    a0[r] += wa.x * h.x + wa.y * h.y + wa.z * h.z + wa.w * h.w;
                    a1[r] += wb.x * h.x + wb.y * h.y + wb.z * h.z + wb.w * h.w;
                }
            }
            float biasA = bih1[tid] + bhh1[tid];
            float biasB = bih1[tid + 256] + bhh1[tid + 256];
            #pragma unroll
            for (int r = 0; r < 4; ++r) {
                s_g1[r][tid] = a0[r] + biasA;
                s_g1[r][tid + 256] = a1[r] + biasB;
            }
        }
        __syncthreads();

        // (c) LSTM1 activations
        for (int i = tid; i < 4 * H1D; i += 256) {
            int r = i >> 7, j = i & 127;
            float gi = s_g1[r][j], gf = s_g1[r][H1D + j];
            float gg = s_g1[r][2 * H1D + j], go = s_g1[r][3 * H1D + j];
            float c = sigmoidf_(gf) * s_c1[r][j] + sigmoidf_(gi) * tanhf(gg);
            s_c1[r][j] = c;
            s_h1[r][j] = sigmoidf_(go) * tanhf(c);
        }
        __syncthreads();

        // (d) g2 = h1 @ Wih2^T + h2 @ Whh2^T + biases  (thread: gate tid; 4 rows)
        {
            float a[4] = {0.f, 0.f, 0.f, 0.f};
            const f32x4* w = (const f32x4*)(Wih2 + (size_t)tid * 128);
            #pragma unroll 4
            for (int k4 = 0; k4 < 32; ++k4) {
                f32x4 ww = w[k4];
                #pragma unroll
                for (int r = 0; r < 4; ++r) {
                    f32x4 h = *(const f32x4*)&s_h1[r][k4 * 4];
                    a[r] += ww.x * h.x + ww.y * h.y + ww.z * h.z + ww.w * h.w;
                }
            }
            const f32x4* w2 = (const f32x4*)(Whh2 + (size_t)tid * 64);
            #pragma unroll 4
            for (int k4 = 0; k4 < 16; ++k4) {
                f32x4 ww = w2[k4];
                #pragma unroll
                for (int r = 0; r < 4; ++r) {
                    f32x4 h = *(const f32x4*)&s_h2[r][k4 * 4];
                    a[r] += ww.x * h.x + ww.y * h.y + ww.z * h.z + ww.w * h.w;
                }
            }
            float bias = bih2[tid] + bhh2[tid];
            #pragma unroll
            for (int r = 0; r < 4; ++r) s_g2[r][tid] = a[r] + bias;
        }
        __syncthreads();

        // (e) LSTM2 activations
        for (int i = tid; i < 4 * H2D; i += 256) {
            int r = i >> 6, j = i & 63;
            float gi = s_g2[r][j], gf = s_g2[r][H2D + j];
            float gg = s_g2[r][2 * H2D + j], go = s_g2[r][3 * H2D + j];
            float c = sigmoidf_(gf) * s_c2[r][j] + sigmoidf_(gi) * tanhf(gg);
            s_c2[r][j] = c;
            s_h2[r][j] = sigmoidf_(go) * tanhf(c);
        }
        __syncthreads();

        // (f) q = h2 @ Wq^T + bq
        {
            int r = tid >> 6, qj = tid & 63;
            float a = bq[qj];
            const f32x4* w = (const f32x4*)(Wq + (size_t)qj * 64);
            #pragma unroll
            for (int k4 = 0; k4 < 16; ++k4) {
                f32x4 ww = w[k4];
                f32x4 h = *(const f32x4*)&s_h2[r][k4 * 4];
                a += ww.x * h.x + ww.y * h.y + ww.z * h.z + ww.w * h.w;
            }
            s_q[r][qj] = a;
        }
        __syncthreads();

        // (g)+(h) attention: wave w owns row w. Lane covers 4 t's.
        {
            const int w = tid >> 6, lane = tid & 63;
            const int b = blk * 4 + w;
            float e[4];
            #pragma unroll
            for (int tt = 0; tt < 4; ++tt) {
                int tk = tt * 64 + lane;
                const f32x4* kp = (const f32x4*)(key + ((size_t)tk * BDIM + b) * QD);
                float acc = 0.f;
                #pragma unroll
                for (int k4 = 0; k4 < 16; ++k4) {
                    f32x4 kk = kp[k4];
                    f32x4 qq = *(const f32x4*)&s_q[w][k4 * 4];
                    acc += kk.x * qq.x + kk.y * qq.y + kk.z * qq.z + kk.w * qq.w;
                }
                e[tt] = acc;
            }
            float mx = fmaxf(fmaxf(e[0], e[1]), fmaxf(e[2], e[3]));
            #pragma unroll
            for (int off = 1; off < 64; off <<= 1) mx = fmaxf(mx, __shfl_xor(mx, off));
            float s1 = 0.f;
            #pragma unroll
            for (int tt = 0; tt < 4; ++tt) { e[tt] = __expf(e[tt] - mx); s1 += e[tt]; }
            #pragma unroll
            for (int off = 1; off < 64; off <<= 1) s1 += __shfl_xor(s1, off);
            float inv1 = 1.f / s1;
            float s2 = 0.f;
            #pragma unroll
            for (int tt = 0; tt < 4; ++tt) {
                int tk = tt * 64 + lane;
                float mv = mask[(size_t)b * TDIM + tk];
                e[tt] = mv * e[tt] * inv1;   // ma = mask * attn
                s2 += e[tt];
            }
            #pragma unroll
            for (int off = 1; off < 64; off <<= 1) s2 += __shfl_xor(s2, off);
            float inv2 = 1.f / fmaxf(s2, 2e-30f);
            #pragma unroll
            for (int tt = 0; tt < 4; ++tt) s_ma[w][tt * 64 + lane] = e[tt] * inv2;

            // ctx[v] = sum_t ma[t] * values[t][b][v]; lane = v (coalesced 256B/iter)
            float acc = 0.f;
            #pragma unroll 4
            for (int tk = 0; tk < TDIM; ++tk)
                acc += s_ma[w][tk] * values[((size_t)tk * BDIM + b) * QD + lane];
            s_ctx[w][lane] = acc;

            _Float16* outp = h2ctx + ((size_t)b * LSTEPS + t) * 128;
            outp[lane] = (_Float16)s_h2[w][lane];
            outp[64 + lane] = (_Float16)acc;
        }
        __syncthreads();
    }
}

// ---------------------------------------------------------------------------
// Kernel B: out[m][v] = h2ctx[m] . W_out[v] + b_out[v], fp16 MFMA 16x16x32.
// M = 14848, N = 5000, K = 128 (single K tile). 64x64 block tile, 4 waves.
// ---------------------------------------------------------------------------
#define KP 136  // padded LDS row (fp16 elems): 272B, uint4-aligned, bank-safe

__global__ __launch_bounds__(256) void k_outproj(
    const _Float16* __restrict__ A,     // [M][128] fp16
    const _Float16* __restrict__ Bw,    // [VOCAB][128] fp16
    const float* __restrict__ b_out,
    float* __restrict__ out)            // [M][VOCAB] fp32
{
    __shared__ _Float16 As[64 * KP];
    __shared__ _Float16 Bs[64 * KP];
    const int tid = threadIdx.x;
    const int m0 = blockIdx.y * 64;
    const int v0 = blockIdx.x * 64;

    // A tile: rows m0..m0+63 are one contiguous 16KB block
    const uint4* Ag = (const uint4*)(A + (size_t)m0 * 128);
    uint4* AsU = (uint4*)As;
    #pragma unroll
    for (int i = 0; i < 4; ++i) {
        int fi = tid + 256 * i;          // uint4 index in tile (16 per row)
        int row = fi >> 4, col = fi & 15;
        AsU[row * 17 + col] = Ag[fi];
    }
    // B tile: rows v0..v0+63 of W_out (zero-fill past VOCAB)
    const uint4* Bg = (const uint4*)Bw;
    uint4* BsU = (uint4*)Bs;
    #pragma unroll
    for (int i = 0; i < 4; ++i) {
        int fi = tid + 256 * i;
        int row = fi >> 4, col = fi & 15;
        int v = v0 + row;
        uint4 val = make_uint4(0u, 0u, 0u, 0u);
        if (v < VOCAB) val = Bg[(size_t)v * 16 + col];
        BsU[row * 17 + col] = val;
    }
    __syncthreads();

    const int wv = tid >> 6, lane = tid & 63;
    const int fm = lane & 15, quad = lane >> 4;

    f32x4 acc[4];
    #pragma unroll
    for (int nt = 0; nt < 4; ++nt) acc[nt] = (f32x4){0.f, 0.f, 0.f, 0.f};

    #pragma unroll
    for (int kt = 0; kt < 4; ++kt) {
        f16x8 af = *(const f16x8*)&As[(16 * wv + fm) * KP + kt * 32 + quad * 8];
        #pragma unroll
        for (int nt = 0; nt < 4; ++nt) {
            f16x8 bf = *(const f16x8*)&Bs[(nt * 16 + fm) * KP + kt * 32 + quad * 8];
            acc[nt] = __builtin_amdgcn_mfma_f32_16x16x32_f16(af, bf, acc[nt], 0, 0, 0);
        }
    }

    // D layout: row = quad*4 + r, col = lane&15 (verified m89/m91)
    #pragma unroll
    for (int nt = 0; nt < 4; ++nt) {
        int v = v0 + nt * 16 + fm;
        if (v < VOCAB) {
            float bo = b_out[v];
            #pragma unroll
            for (int r = 0; r < 4; ++r) {
                int row = m0 + 16 * wv + quad * 4 + r;
                out[(size_t)row * VOCAB + v] = acc[nt][r] + bo;
            }
        }
    }
}

// ---------------------------------------------------------------------------
__global__ __launch_bounds__(256) void k_cvt_f16(const float* __restrict__ W,
                                                 _Float16* __restrict__ Wh, int n) {
    int i = blockIdx.x * 256 + threadIdx.x;
    if (i < n) Wh[i] = (_Float16)W[i];
}

extern "C" void kernel_launch(void* const* d_in, const int* in_sizes, int n_in,
                              void* d_out, int out_size, void* d_ws, size_t ws_size,
                              hipStream_t stream) {
    const float* key    = (const float*)d_in[0];
    const float* values = (const float*)d_in[1];
    const float* mask   = (const float*)d_in[2];
    const int*   text   = (const int*)d_in[3];
    const float* emb    = (const float*)d_in[4];
    const float* Wih1   = (const float*)d_in[5];
    const float* Whh1   = (const float*)d_in[6];
    const float* bih1   = (const float*)d_in[7];
    const float* bhh1   = (const float*)d_in[8];
    const float* Wih2   = (const float*)d_in[9];
    const float* Whh2   = (const float*)d_in[10];
    const float* bih2   = (const float*)d_in[11];
    const float* bhh2   = (const float*)d_in[12];
    const float* Wq     = (const float*)d_in[13];
    const float* bq     = (const float*)d_in[14];
    const float* Wout   = (const float*)d_in[15];
    const float* bout   = (const float*)d_in[16];
    float* out = (float*)d_out;

    // ws layout: [0, 2MB) W_out fp16 (1.28MB + OOB-read slack); [2MB, ~5.9MB) h2ctx fp16
    _Float16* WoutH = (_Float16*)d_ws;
    _Float16* h2ctx = (_Float16*)((char*)d_ws + (2u << 20));

    k_cvt_f16<<<dim3((VOCAB * EMB + 255) / 256), dim3(256), 0, stream>>>(Wout, WoutH, VOCAB * EMB);
    k_recurrent<<<dim3(BDIM / 4), dim3(256), 0, stream>>>(
        key, values, mask, text, emb,
        Wih1, Whh1, bih1, bhh1, Wih2, Whh2, bih2, bhh2, Wq, bq, h2ctx);
    k_outproj<<<dim3((VOCAB + 63) / 64, (BDIM * LSTEPS) / 64), dim3(256), 0, stream>>>(
        h2ctx, WoutH, bout, out);
}

// Round 2
// 1356.561 us; speedup vs baseline: 1.4544x; 1.4544x over previous
//
#include <hip/hip_runtime.h>
#include <hip/hip_bf16.h>
#include <hip/hip_fp16.h>

#define VOCAB 5000
#define EMB 128
#define H1D 128
#define H2D 64
#define QD 64
#define TDIM 256
#define BDIM 512
#define LTEXT 30
#define LSTEPS 29

typedef __attribute__((ext_vector_type(4))) float f32x4;
typedef __attribute__((ext_vector_type(8))) _Float16 f16x8;
typedef __attribute__((ext_vector_type(2))) _Float16 h2v;

// ---- workspace layout (bytes) ----
#define OFF_WOUT  0u                    // 5000*128 fp16 = 1,280,000
#define OFF_W1H   0x140000u             // 512*320 fp16  =   327,680
#define OFF_W2H   (OFF_W1H + 512u*320u*2u)
#define OFF_WQH   (OFF_W2H + 256u*192u*2u)
#define OFF_B1    (OFF_WQH + 64u*64u*2u)
#define OFF_B2    (OFF_B1 + 512u*4u)
#define OFF_H2CTX 0x1B0000u             // 14848*128 fp16 = 3,801,088

__device__ __forceinline__ float sigmoidf_(float x) {
    return 1.0f / (1.0f + __expf(-x));
}

__device__ __forceinline__ float dot8(f16x8 w, f16x8 u, float acc) {
    union U8 { f16x8 v; h2v h[4]; };
    U8 W; W.v = w; U8 X; X.v = u;
#if __has_builtin(__builtin_amdgcn_fdot2)
    acc = __builtin_amdgcn_fdot2(W.h[0], X.h[0], acc, false);
    acc = __builtin_amdgcn_fdot2(W.h[1], X.h[1], acc, false);
    acc = __builtin_amdgcn_fdot2(W.h[2], X.h[2], acc, false);
    acc = __builtin_amdgcn_fdot2(W.h[3], X.h[3], acc, false);
#else
    #pragma unroll
    for (int i = 0; i < 8; ++i) acc += (float)w[i] * (float)u[i];
#endif
    return acc;
}

// ---------------------------------------------------------------------------
// Prep kernels: pack weights to fp16, fold biases.
// ---------------------------------------------------------------------------
__global__ void k_cvt_f16(const float* __restrict__ W, _Float16* __restrict__ Wh, int n) {
    int i = blockIdx.x * 256 + threadIdx.x;
    if (i < n) Wh[i] = (_Float16)W[i];
}

__global__ void k_prep_w1(const float* __restrict__ Wih1, const float* __restrict__ Whh1,
                          const float* __restrict__ bih1, const float* __restrict__ bhh1,
                          _Float16* __restrict__ W1h, float* __restrict__ bias1) {
    int g = blockIdx.x;          // 512
    int k = threadIdx.x;         // 320
    float v = (k < 192) ? Wih1[g * 192 + k] : Whh1[g * 128 + (k - 192)];
    W1h[g * 320 + k] = (_Float16)v;
    if (k == 0) bias1[g] = bih1[g] + bhh1[g];
}

__global__ void k_prep_w2(const float* __restrict__ Wih2, const float* __restrict__ Whh2,
                          const float* __restrict__ bih2, const float* __restrict__ bhh2,
                          _Float16* __restrict__ W2h, float* __restrict__ bias2) {
    int g = blockIdx.x;          // 256
    int k = threadIdx.x;         // 192
    float v = (k < 128) ? Wih2[g * 128 + k] : Whh2[g * 64 + (k - 128)];
    W2h[g * 192 + k] = (_Float16)v;
    if (k == 0) bias2[g] = bih2[g] + bhh2[g];
}

// ---------------------------------------------------------------------------
// Kernel A v2: 256 blocks x 512 threads, 2 rows/block.
// Per step: u=[x|ctx|h1] fp16 -> g1 (1 thread = 1 gate, both rows) -> LSTM1
//           v=[h1|h2] fp16 -> g2 -> LSTM2 -> q -> attention -> ctx.
// ---------------------------------------------------------------------------
__global__ __launch_bounds__(512, 2) void k_recurrent(
    const float* __restrict__ key, const float* __restrict__ values,
    const float* __restrict__ mask, const int* __restrict__ text,
    const float* __restrict__ emb,
    const _Float16* __restrict__ W1h, const float* __restrict__ bias1,
    const _Float16* __restrict__ W2h, const float* __restrict__ bias2,
    const _Float16* __restrict__ Wqh, const float* __restrict__ bq,
    _Float16* __restrict__ h2ctx)
{
    __shared__ alignas(16) _Float16 s_u16[2][320];   // [x(128)|ctx(64)|h1(128)]
    __shared__ alignas(16) _Float16 s_v16[2][192];   // [h1(128)|h2(64)]
    __shared__ float s_g1[2][512];
    __shared__ float s_g2[2][256];
    __shared__ float s_c1[2][128], s_h1[2][128];
    __shared__ float s_c2[2][64];
    __shared__ alignas(16) float s_q[2][64];
    __shared__ float s_e[2][256];
    __shared__ float s_ma[2][256];
    __shared__ float s_cp[2][4][64];
    __shared__ float s_ctx[2][64];
    __shared__ float s_redM[8], s_redA[8], s_redB[8];

    const int tid = threadIdx.x;
    const int blk = blockIdx.x;
    const int b0 = blk * 2;

    // zero init recurrent state
    for (int i = tid; i < 256; i += 512) {
        s_c1[i >> 7][i & 127] = 0.f;
        s_h1[i >> 7][i & 127] = 0.f;
    }
    if (tid < 128) {
        int r = tid >> 6, j = tid & 63;
        s_c2[r][j] = 0.f;
        s_ctx[r][j] = 0.f;
        s_v16[r][128 + j] = (_Float16)0.f;
    }
    __syncthreads();

    for (int t = 0; t < LSTEPS; ++t) {
        // ---- (a) build u = [x | ctx | h1] as fp16 ----
        for (int i = tid; i < 640; i += 512) {
            if (i < 256) {
                int r = i >> 7, k = i & 127;
                int tok = text[(b0 + r) * LTEXT + t];
                s_u16[r][k] = (_Float16)emb[(size_t)tok * EMB + k];
            } else if (i < 384) {
                int j = i - 256; int r = j >> 6, k = j & 63;
                s_u16[r][128 + k] = (_Float16)s_ctx[r][k];
            } else {
                int j = i - 384; int r = j >> 7, k = j & 127;
                s_u16[r][192 + k] = (_Float16)s_h1[r][k];
            }
        }
        __syncthreads();

        // ---- (b) g1: thread = gate (512), both rows; W row from global (L2) ----
        {
            const f16x8* wrow = (const f16x8*)(W1h + (size_t)tid * 320);
            const f16x8* u0 = (const f16x8*)&s_u16[0][0];
            const f16x8* u1 = (const f16x8*)&s_u16[1][0];
            float a0 = bias1[tid], a1 = a0;
            #pragma unroll 8
            for (int c = 0; c < 40; ++c) {
                f16x8 w = wrow[c];
                a0 = dot8(w, u0[c], a0);
                a1 = dot8(w, u1[c], a1);
            }
            s_g1[0][tid] = a0;
            s_g1[1][tid] = a1;
        }
        __syncthreads();

        // ---- (c) LSTM1 activations (256 units) ----
        if (tid < 256) {
            int r = tid >> 7, j = tid & 127;
            float gi = s_g1[r][j], gf = s_g1[r][128 + j];
            float gg = s_g1[r][256 + j], go = s_g1[r][384 + j];
            float c = sigmoidf_(gf) * s_c1[r][j] + sigmoidf_(gi) * tanhf(gg);
            float h = sigmoidf_(go) * tanhf(c);
            s_c1[r][j] = c;
            s_h1[r][j] = h;            // fp32 for next-step u
            s_v16[r][j] = (_Float16)h; // fp16 for layer 2 now
        }
        __syncthreads();

        // ---- (d) g2: thread = (gate=tid&255, row=tid>>8) ----
        {
            int g = tid & 255, r = tid >> 8;
            const f16x8* wrow = (const f16x8*)(W2h + (size_t)g * 192);
            const f16x8* vv = (const f16x8*)&s_v16[r][0];
            float a = bias2[g];
            #pragma unroll 8
            for (int c = 0; c < 24; ++c)
                a = dot8(wrow[c], vv[c], a);
            s_g2[r][g] = a;
        }
        __syncthreads();

        // ---- (e) LSTM2 activations (128 units); also store h2 to h2ctx ----
        if (tid < 128) {
            int r = tid >> 6, j = tid & 63;
            float gi = s_g2[r][j], gf = s_g2[r][64 + j];
            float gg = s_g2[r][128 + j], go = s_g2[r][192 + j];
            float c = sigmoidf_(gf) * s_c2[r][j] + sigmoidf_(gi) * tanhf(gg);
            float h = sigmoidf_(go) * tanhf(c);
            s_c2[r][j] = c;
            s_v16[r][128 + j] = (_Float16)h;   // h2_prev for next step + q input
            h2ctx[((size_t)(b0 + r) * LSTEPS + t) * 128 + j] = (_Float16)h;
        }
        __syncthreads();

        // ---- (f) q = Wq @ h2 + bq (128 outputs, full dot per thread) ----
        if (tid < 128) {
            int r = tid >> 6, qj = tid & 63;
            const f16x8* wrow = (const f16x8*)(Wqh + (size_t)qj * 64);
            const f16x8* hv = (const f16x8*)&s_v16[r][128];
            float a = bq[qj];
            #pragma unroll
            for (int c = 0; c < 8; ++c)
                a = dot8(wrow[c], hv[c], a);
            s_q[r][qj] = a;
        }
        __syncthreads();

        // ---- (g) energies: thread = (row=tid>>8, tk=tid&255) ----
        const int row = tid >> 8, tk = tid & 255;
        const int b = b0 + row;
        float e;
        {
            const f32x4* kp = (const f32x4*)(key + ((size_t)tk * BDIM + b) * QD);
            const f32x4* qp = (const f32x4*)&s_q[row][0];
            float acc = 0.f;
            #pragma unroll
            for (int c = 0; c < 16; ++c) {
                f32x4 kk = kp[c], qq = qp[c];
                acc += kk.x * qq.x + kk.y * qq.y + kk.z * qq.z + kk.w * qq.w;
            }
            e = acc;
        }
        // ---- (h) softmax: max ----
        {
            const int wave = tid >> 6, lane = tid & 63;
            float m = e;
            #pragma unroll
            for (int off = 1; off < 64; off <<= 1) m = fmaxf(m, __shfl_xor(m, off));
            if (lane == 0) s_redM[wave] = m;
            __syncthreads();
            float mrow = fmaxf(fmaxf(s_redM[row * 4], s_redM[row * 4 + 1]),
                               fmaxf(s_redM[row * 4 + 2], s_redM[row * 4 + 3]));
            float p = __expf(e - mrow);
            float mp = mask[(size_t)b * TDIM + tk] * p;
            float sp = p, smp = mp;
            #pragma unroll
            for (int off = 1; off < 64; off <<= 1) {
                sp += __shfl_xor(sp, off);
                smp += __shfl_xor(smp, off);
            }
            if (lane == 0) { s_redA[wave] = sp; s_redB[wave] = smp; }
            __syncthreads();
            float s1 = s_redA[row * 4] + s_redA[row * 4 + 1] + s_redA[row * 4 + 2] + s_redA[row * 4 + 3];
            float S2 = s_redB[row * 4] + s_redB[row * 4 + 1] + s_redB[row * 4 + 2] + s_redB[row * 4 + 3];
            float denom = fmaxf(S2, 2e-30f * s1);
            s_ma[row][tk] = mp / denom;
        }
        __syncthreads();

        // ---- (i) ctx: thread = (row, v=tid&63, chunk=(tid>>6)&3) ----
        {
            int v = tid & 63, chunk = (tid >> 6) & 3;
            const float* vp = values + ((size_t)(chunk * 64) * BDIM + b) * QD + v;
            const float* map = &s_ma[row][chunk * 64];
            float acc = 0.f;
            #pragma unroll 8
            for (int k = 0; k < 64; ++k)
                acc += map[k] * vp[(size_t)k * BDIM * QD];
            s_cp[row][chunk][v] = acc;
        }
        __syncthreads();
        if (tid < 128) {
            int r = tid >> 6, v = tid & 63;
            float c = s_cp[r][0][v] + s_cp[r][1][v] + s_cp[r][2][v] + s_cp[r][3][v];
            s_ctx[r][v] = c;
            h2ctx[((size_t)(b0 + r) * LSTEPS + t) * 128 + 64 + v] = (_Float16)c;
        }
        __syncthreads();
    }
}

// ---------------------------------------------------------------------------
// Kernel B: out = h2ctx @ W_out^T + b_out, fp16 MFMA 16x16x32.
// M = 14848, N = 5000, K = 128. 64x64 tile, 4 waves.
// ---------------------------------------------------------------------------
#define KP 136

__global__ __launch_bounds__(256) void k_outproj(
    const _Float16* __restrict__ A,
    const _Float16* __restrict__ Bw,
    const float* __restrict__ b_out,
    float* __restrict__ out)
{
    __shared__ _Float16 As[64 * KP];
    __shared__ _Float16 Bs[64 * KP];
    const int tid = threadIdx.x;
    const int m0 = blockIdx.y * 64;
    const int v0 = blockIdx.x * 64;

    const uint4* Ag = (const uint4*)(A + (size_t)m0 * 128);
    uint4* AsU = (uint4*)As;
    #pragma unroll
    for (int i = 0; i < 4; ++i) {
        int fi = tid + 256 * i;
        int r = fi >> 4, c = fi & 15;
        AsU[r * 17 + c] = Ag[fi];
    }
    const uint4* Bg = (const uint4*)Bw;
    uint4* BsU = (uint4*)Bs;
    #pragma unroll
    for (int i = 0; i < 4; ++i) {
        int fi = tid + 256 * i;
        int r = fi >> 4, c = fi & 15;
        int v = v0 + r;
        uint4 val = make_uint4(0u, 0u, 0u, 0u);
        if (v < VOCAB) val = Bg[(size_t)v * 16 + c];
        BsU[r * 17 + c] = val;
    }
    __syncthreads();

    const int wv = tid >> 6, lane = tid & 63;
    const int fm = lane & 15, quad = lane >> 4;

    f32x4 acc[4];
    #pragma unroll
    for (int nt = 0; nt < 4; ++nt) acc[nt] = (f32x4){0.f, 0.f, 0.f, 0.f};

    #pragma unroll
    for (int kt = 0; kt < 4; ++kt) {
        f16x8 af = *(const f16x8*)&As[(16 * wv + fm) * KP + kt * 32 + quad * 8];
        #pragma unroll
        for (int nt = 0; nt < 4; ++nt) {
            f16x8 bf = *(const f16x8*)&Bs[(nt * 16 + fm) * KP + kt * 32 + quad * 8];
            acc[nt] = __builtin_amdgcn_mfma_f32_16x16x32_f16(af, bf, acc[nt], 0, 0, 0);
        }
    }

    #pragma unroll
    for (int nt = 0; nt < 4; ++nt) {
        int v = v0 + nt * 16 + fm;
        if (v < VOCAB) {
            float bo = b_out[v];
            #pragma unroll
            for (int r = 0; r < 4; ++r) {
                int rowm = m0 + 16 * wv + quad * 4 + r;
                out[(size_t)rowm * VOCAB + v] = acc[nt][r] + bo;
            }
        }
    }
}

extern "C" void kernel_launch(void* const* d_in, const int* in_sizes, int n_in,
                              void* d_out, int out_size, void* d_ws, size_t ws_size,
                              hipStream_t stream) {
    const float* key    = (const float*)d_in[0];
    const float* values = (const float*)d_in[1];
    const float* mask   = (const float*)d_in[2];
    const int*   text   = (const int*)d_in[3];
    const float* emb    = (const float*)d_in[4];
    const float* Wih1   = (const float*)d_in[5];
    const float* Whh1   = (const float*)d_in[6];
    const float* bih1   = (const float*)d_in[7];
    const float* bhh1   = (const float*)d_in[8];
    const float* Wih2   = (const float*)d_in[9];
    const float* Whh2   = (const float*)d_in[10];
    const float* bih2   = (const float*)d_in[11];
    const float* bhh2   = (const float*)d_in[12];
    const float* Wq     = (const float*)d_in[13];
    const float* bq     = (const float*)d_in[14];
    const float* Wout   = (const float*)d_in[15];
    const float* bout   = (const float*)d_in[16];
    float* out = (float*)d_out;

    char* ws = (char*)d_ws;
    _Float16* WoutH = (_Float16*)(ws + OFF_WOUT);
    _Float16* W1h   = (_Float16*)(ws + OFF_W1H);
    _Float16* W2h   = (_Float16*)(ws + OFF_W2H);
    _Float16* Wqh   = (_Float16*)(ws + OFF_WQH);
    float*    bias1 = (float*)(ws + OFF_B1);
    float*    bias2 = (float*)(ws + OFF_B2);
    _Float16* h2ctx = (_Float16*)(ws + OFF_H2CTX);

    k_cvt_f16<<<dim3((VOCAB * EMB + 255) / 256), dim3(256), 0, stream>>>(Wout, WoutH, VOCAB * EMB);
    k_cvt_f16<<<dim3(16), dim3(256), 0, stream>>>(Wq, Wqh, QD * H2D);
    k_prep_w1<<<dim3(512), dim3(320), 0, stream>>>(Wih1, Whh1, bih1, bhh1, W1h, bias1);
    k_prep_w2<<<dim3(256), dim3(192), 0, stream>>>(Wih2, Whh2, bih2, bhh2, W2h, bias2);

    k_recurrent<<<dim3(BDIM / 2), dim3(512), 0, stream>>>(
        key, values, mask, text, emb, W1h, bias1, W2h, bias2, Wqh, bq, h2ctx);

    k_outproj<<<dim3((VOCAB + 63) / 64, (BDIM * LSTEPS) / 64), dim3(256), 0, stream>>>(
        h2ctx, WoutH, bout, out);
}